// Round 11
// baseline (370.716 us; speedup 1.0000x reference)
//
#include <hip/hip_runtime.h>
#include <math.h>

typedef __attribute__((ext_vector_type(8))) short short8;
typedef __attribute__((ext_vector_type(4))) short s16x4;
typedef __attribute__((ext_vector_type(4))) float floatx4;

__device__ __forceinline__ float bits2f(short u) {
  unsigned int x = ((unsigned int)(unsigned short)u) << 16;
  return __builtin_bit_cast(float, x);
}
__device__ __forceinline__ short f2bits(float f) {
  unsigned int x = __builtin_bit_cast(unsigned int, f);
  x += 0x7FFFu + ((x >> 16) & 1u);   // RNE
  return (short)(x >> 16);
}

__device__ __forceinline__ void gload_lds16(const short* g, short* l) {
  __builtin_amdgcn_global_load_lds((const __attribute__((address_space(1))) void*)g,
                                   (__attribute__((address_space(3))) void*)l, 16, 0, 0);
}

// ---------------------------------------------------------------------------
// f32 -> bf16 (RNE), 8 elems/thread, grid-stride. n8 = n_elems/8.
// ---------------------------------------------------------------------------
__global__ __launch_bounds__(256) void cvt_bf16(const float* __restrict__ in,
                                                short* __restrict__ out, long n8) {
  long i = (long)blockIdx.x * 256 + threadIdx.x;
  const long stride = (long)gridDim.x * 256;
  for (; i < n8; i += stride) {
    const floatx4* p = (const floatx4*)(in + i * 8);
    floatx4 v0 = p[0], v1 = p[1];
    short8 o;
#pragma unroll
    for (int e = 0; e < 4; e++) { o[e] = f2bits(v0[e]); o[e + 4] = f2bits(v1[e]); }
    *(short8*)(out + i * 8) = o;
  }
}

// ---------------------------------------------------------------------------
// rope table: tab[t][j] = {cos(t*inv_j), sin(t*inv_j)} interleaved f32.
// ---------------------------------------------------------------------------
__global__ __launch_bounds__(256) void rope_table(float* __restrict__ tab) {
  int i = blockIdx.x * 256 + threadIdx.x;   // 0..2047
  if (i >= 64 * 32) return;
  int t = i >> 5, j = i & 31;
  float inv = exp2f(-(float)j * 0.41524101186092030f);  // 10000^(-j/32)
  float ang = (float)t * inv;
  tab[i * 2]     = cosf(ang);
  tab[i * 2 + 1] = sinf(ang);
}

// ---------------------------------------------------------------------------
// C[m][n] = sum_k A[m][k]*B[n][k], bf16 in, fp32 acc. 256x256 tile, BK=32,
// 8 waves (2M x 4N, wave tile 128x64), ring-4 LDS pipeline (4 x 32KB slots),
// counted vmcnt (never 0 in main loop), raw s_barrier, setprio on MFMA.
// Bank swizzle (rule 21 both-sides): LDS dest stays linear for
// global_load_lds; the global SOURCE k-chunk is permuted slot^((row>>1)&3)
// and the ds_read applies the same involution.  [R7: conflicts 9.4M -> 0]
// Requires M%256==0, N%256==0, K%32==0, K>=128, gridDim.x%8==0.
// ---------------------------------------------------------------------------
template <bool COUT_F32>
__global__ __launch_bounds__(512, 2) void gemm256(const short* __restrict__ A,
                                                  const short* __restrict__ B,
                                                  void* __restrict__ C,
                                                  int M, int N, int K) {
  (void)M;
  __shared__ __attribute__((aligned(16))) short lds[65536];  // 4 slots x (A 16KB | B 16KB)

  const int t    = threadIdx.x;          // 0..511
  const int lane = t & 63;
  const int wave = t >> 6;               // 0..7
  const int wm   = wave >> 2;            // 0..1
  const int wn   = wave & 3;             // 0..3
  const int frow = lane & 15;
  const int quad = lane >> 4;

  // bijective XCD-aware swizzle (gridDim.x % 8 == 0)
  const int nwg = gridDim.x;
  const int cpx = nwg >> 3;
  const int bid = blockIdx.x;
  const int swz = (bid & 7) * cpx + (bid >> 3);
  const int nbx = N >> 8;
  const int bx  = swz % nbx;
  const int by  = swz / nbx;
  const long m0 = (long)by * 256;
  const long n0 = (long)bx * 256;

  const int NT = K >> 5;                 // K-tiles of 32

  // staging: thread t -> LDS (row=t>>2, slot=t&3) linear; global k-chunk = slot^((row>>1)&3)
  const int  srow  = t >> 2;             // 0..127
  const int  scol  = ((t & 3) ^ ((srow >> 1) & 3)) * 8;   // pre-permuted source col
  const long aoff0 = (m0 + srow) * (long)K + scol;
  const long aoff1 = aoff0 + 128L * K;
  const long boff0 = (n0 + srow) * (long)K + scol;
  const long boff1 = boff0 + 128L * K;
  const int  t8    = t * 8;              // linear LDS dest (shorts)

  // fragment read: logical k-chunk quad lives at LDS slot quad^((frow>>1)&3)
  const int sw8 = (quad ^ ((frow >> 1) & 3)) * 8;

  floatx4 acc[8][4];
#pragma unroll
  for (int i = 0; i < 8; i++)
#pragma unroll
    for (int j = 0; j < 4; j++) acc[i][j] = (floatx4){0.f, 0.f, 0.f, 0.f};

  // prologue: stage tiles 0,1,2 into slots 0,1,2 (12 issues/thread)
  for (int p = 0; p < 3; ++p) {
    short* la = lds + p * 16384;
    const long kk = (long)p * 32;
    gload_lds16(A + aoff0 + kk, la + t8);
    gload_lds16(A + aoff1 + kk, la + t8 + 4096);
    gload_lds16(B + boff0 + kk, la + 8192 + t8);
    gload_lds16(B + boff1 + kk, la + 8192 + t8 + 4096);
  }

#define GSTEP(KT, VMSTR, DO_STAGE)                                                     \
  {                                                                                    \
    const int kt_ = (KT);                                                              \
    asm volatile("s_barrier" ::: "memory");  /* all waves done reading slot kt_-1 */   \
    if (DO_STAGE) {                                                                    \
      short* sa = lds + ((kt_ + 3) & 3) * 16384;                                       \
      const long kk = (long)(kt_ + 3) * 32;                                            \
      gload_lds16(A + aoff0 + kk, sa + t8);                                            \
      gload_lds16(A + aoff1 + kk, sa + t8 + 4096);                                     \
    }                                                                                  \
    asm volatile("s_waitcnt " VMSTR ::: "memory");  /* own share of tile kt_ landed */ \
    asm volatile("s_barrier" ::: "memory");         /* everyone's share landed */      \
    {                                                                                  \
      const short* la = lds + (kt_ & 3) * 16384;                                       \
      const short* lb = la + 8192;                                                     \
      short8 af[8], bf[4];                                                             \
      _Pragma("unroll")                                                                \
      for (int ni = 0; ni < 4; ni++)                                                   \
        bf[ni] = *(const short8*)&lb[(wn * 64 + ni * 16 + frow) * 32 + sw8];           \
      _Pragma("unroll")                                                                \
      for (int mi = 0; mi < 8; mi++)                                                   \
        af[mi] = *(const short8*)&la[(wm * 128 + mi * 16 + frow) * 32 + sw8];          \
      __builtin_amdgcn_s_setprio(1);                                                   \
      _Pragma("unroll")                                                                \
      for (int mi = 0; mi < 4; mi++)                                                   \
        _Pragma("unroll")                                                              \
        for (int ni = 0; ni < 4; ni++)                                                 \
          acc[mi][ni] =                                                                \
              __builtin_amdgcn_mfma_f32_16x16x32_bf16(af[mi], bf[ni], acc[mi][ni], 0, 0, 0); \
      __builtin_amdgcn_s_setprio(0);                                                   \
      if (DO_STAGE) {                                                                  \
        short* sb = lds + ((kt_ + 3) & 3) * 16384;                                     \
        const long kk = (long)(kt_ + 3) * 32;                                          \
        gload_lds16(B + boff0 + kk, sb + 8192 + t8);                                   \
        gload_lds16(B + boff1 + kk, sb + 8192 + t8 + 4096);                            \
      }                                                                                \
      __builtin_amdgcn_s_setprio(1);                                                   \
      _Pragma("unroll")                                                                \
      for (int mi = 4; mi < 8; mi++)                                                   \
        _Pragma("unroll")                                                              \
        for (int ni = 0; ni < 4; ni++)                                                 \
          acc[mi][ni] =                                                                \
              __builtin_amdgcn_mfma_f32_16x16x32_bf16(af[mi], bf[ni], acc[mi][ni], 0, 0, 0); \
      __builtin_amdgcn_s_setprio(0);                                                   \
    }                                                                                  \
  }

  // main loop: tiles kt+1,kt+2 fully in flight + stageA(kt+3) = 10 outstanding
  for (int kt = 0; kt <= NT - 4; ++kt) GSTEP(kt, "vmcnt(10)", true);
  GSTEP(NT - 3, "vmcnt(8)", false);
  GSTEP(NT - 2, "vmcnt(4)", false);
  GSTEP(NT - 1, "vmcnt(0)", false);
#undef GSTEP

  // epilogue: C/D layout col=lane&15, row=quad*4+r (verified convention)
  const long mrow0 = m0 + wm * 128;
  const long ncol0 = n0 + wn * 64;
#pragma unroll
  for (int mi = 0; mi < 8; mi++)
#pragma unroll
    for (int ni = 0; ni < 4; ni++) {
      long row0 = mrow0 + mi * 16 + quad * 4;
      long col  = ncol0 + ni * 16 + frow;
#pragma unroll
      for (int r = 0; r < 4; r++) {
        if constexpr (COUT_F32)
          ((float*)C)[(row0 + r) * (long)N + col] = acc[mi][ni][r];
        else
          ((short*)C)[(row0 + r) * (long)N + col] = f2bits(acc[mi][ni][r]);
      }
    }
}

// ---------------------------------------------------------------------------
// Q-striped MFMA attention: 1 wave (64 thr) per (head, stripe, chunk, batch).
// blockIdx.x = h*4 + qs; the block computes q-rows [16qs,16qs+16) of the
// chunk: S-stripe = 8 MFMAs, softmax, P->LDS, PV = 8 MFMAs, direct store.
// Mechanical specialization of the R10-verified 1-wave kernel (mi -> grid);
// all lane mappings and both __syncthreads identical to the proven code.
// LDS 10.6 KB -> 15 waves/CU (was 9).
// ---------------------------------------------------------------------------
__global__ __launch_bounds__(64, 1) void attn_stripe(const short* __restrict__ qkv,
                                                     short* __restrict__ y,
                                                     const float* __restrict__ cstab) {
  const int lane = threadIdx.x;
  const int frow = lane & 15;
  const int quad = lane >> 4;
  const int h = blockIdx.x >> 2, qs = blockIdx.x & 3;
  const int chunk = blockIdx.y, b = blockIdx.z;
  const long rowbase = (long)b * 4096 + (long)chunk * 64;

  __shared__ __attribute__((aligned(16))) short vt[64][68];  // V^T: vt[d][j]
  __shared__ __attribute__((aligned(16))) short ps[16][68];  // P stripe

  const short* qb = qkv + rowbase * 3072 + h * 64;

#define CS_(k) ((k) < 4 ? tv0[(k) & 3] : (k) < 8 ? tv1[(k) & 3] : (k) < 12 ? tv2[(k) & 3] : tv3[(k) & 3])
  // ---- Q fragment (stripe qs) + rope ----
  short8 qf[2];
  {
    const short* rq = qb + (long)(16 * qs + frow) * 3072 + quad * 8;
    qf[0] = *(const short8*)(rq);
    qf[1] = *(const short8*)(rq + 32);
    const floatx4* tp = (const floatx4*)(cstab + ((16 * qs + frow) * 32 + quad * 8) * 2);
    floatx4 tv0 = tp[0], tv1 = tp[1], tv2 = tp[2], tv3 = tp[3];
#pragma unroll
    for (int e = 0; e < 8; e++) {
      float c = CS_(2 * e), s = CS_(2 * e + 1);
      float a0 = bits2f(qf[0][e]), a1 = bits2f(qf[1][e]);
      qf[0][e] = f2bits(a0 * c + a1 * s);
      qf[1][e] = f2bits(a1 * c - a0 * s);
    }
  }

  // ---- K fragments (all 4 k-blocks) + rope ----
  short8 kf[4][2];
#pragma unroll
  for (int i = 0; i < 4; i++) {
    const short* rk = qb + (long)(16 * i + frow) * 3072 + quad * 8;
    kf[i][0] = *(const short8*)(rk + 1024);
    kf[i][1] = *(const short8*)(rk + 1056);
    const floatx4* tp = (const floatx4*)(cstab + ((16 * i + frow) * 32 + quad * 8) * 2);
    floatx4 tv0 = tp[0], tv1 = tp[1], tv2 = tp[2], tv3 = tp[3];
#pragma unroll
    for (int e = 0; e < 8; e++) {
      float c = CS_(2 * e), s = CS_(2 * e + 1);
      float b0 = bits2f(kf[i][0][e]), b1 = bits2f(kf[i][1][e]);
      kf[i][0][e] = f2bits(b0 * c + b1 * s);
      kf[i][1][e] = f2bits(b1 * c - b0 * s);
    }
  }
#undef CS_

  // ---- V -> LDS transposed ----
  const short* vb = qb + 2048 + (long)lane * 3072;
#pragma unroll
  for (int w = 0; w < 8; w++) {
    short8 v8 = *(const short8*)(vb + w * 8);
#pragma unroll
    for (int e = 0; e < 8; e++) vt[w * 8 + e][lane] = v8[e];
  }
  __syncthreads();

  // ---- S stripe = Q.K^T (8 MFMAs): rows q=16qs+4quad+r, cols k=16ni+frow
  floatx4 sc[4];
#pragma unroll
  for (int ni = 0; ni < 4; ni++) {
    sc[ni] = (floatx4){0.f, 0.f, 0.f, 0.f};
    sc[ni] = __builtin_amdgcn_mfma_f32_16x16x32_bf16(qf[0], kf[ni][0], sc[ni], 0, 0, 0);
    sc[ni] = __builtin_amdgcn_mfma_f32_16x16x32_bf16(qf[1], kf[ni][1], sc[ni], 0, 0, 0);
  }

  // ---- softmax per q-row ----
  float is_[4];
#pragma unroll
  for (int r = 0; r < 4; r++) {
    float mx = fmaxf(fmaxf(sc[0][r], sc[1][r]), fmaxf(sc[2][r], sc[3][r]));
    mx = fmaxf(mx, __shfl_xor(mx, 1));
    mx = fmaxf(mx, __shfl_xor(mx, 2));
    mx = fmaxf(mx, __shfl_xor(mx, 4));
    mx = fmaxf(mx, __shfl_xor(mx, 8));
    float sm = 0.f;
#pragma unroll
    for (int ni = 0; ni < 4; ni++) {
      float e_ = __expf((sc[ni][r] - mx) * 0.125f);   // scale 1/sqrt(64)
      sc[ni][r] = e_;
      sm += e_;
    }
    sm += __shfl_xor(sm, 1);
    sm += __shfl_xor(sm, 2);
    sm += __shfl_xor(sm, 4);
    sm += __shfl_xor(sm, 8);
    is_[r] = 1.0f / sm;
  }

  // ---- P -> LDS stripe ----
#pragma unroll
  for (int ni = 0; ni < 4; ni++)
#pragma unroll
    for (int r = 0; r < 4; r++)
      ps[quad * 4 + r][ni * 16 + frow] = f2bits(sc[ni][r] * is_[r]);
  __syncthreads();

  // ---- P, V^T fragments ----
  short8 pf[2], vf[4][2];
#pragma unroll
  for (int ks = 0; ks < 2; ks++) {
    const short* pp = &ps[frow][quad * 8 + 32 * ks];
    s16x4 p0 = *(const s16x4*)pp, p1 = *(const s16x4*)(pp + 4);
#pragma unroll
    for (int e = 0; e < 4; e++) { pf[ks][e] = p0[e]; pf[ks][e + 4] = p1[e]; }
  }
#pragma unroll
  for (int ni = 0; ni < 4; ni++)
#pragma unroll
    for (int ks = 0; ks < 2; ks++) {
      const short* vp = &vt[ni * 16 + frow][quad * 8 + 32 * ks];
      s16x4 v0 = *(const s16x4*)vp, v1 = *(const s16x4*)(vp + 4);
#pragma unroll
      for (int e = 0; e < 4; e++) { vf[ni][ks][e] = v0[e]; vf[ni][ks][e + 4] = v1[e]; }
    }

  // ---- Y stripe = P.V (8 MFMAs) ----
  floatx4 oc[4];
#pragma unroll
  for (int ni = 0; ni < 4; ni++) {
    oc[ni] = (floatx4){0.f, 0.f, 0.f, 0.f};
    oc[ni] = __builtin_amdgcn_mfma_f32_16x16x32_bf16(pf[0], vf[ni][0], oc[ni], 0, 0, 0);
    oc[ni] = __builtin_amdgcn_mfma_f32_16x16x32_bf16(pf[1], vf[ni][1], oc[ni], 0, 0, 0);
  }

  // ---- direct store (q = 16qs+4quad+r, d = 16ni+frow) ----
#pragma unroll
  for (int ni = 0; ni < 4; ni++)
#pragma unroll
    for (int r = 0; r < 4; r++)
      y[(rowbase + 16 * qs + quad * 4 + r) * 1024 + h * 64 + ni * 16 + frow] =
          f2bits(oc[ni][r]);
}

// ---------------------------------------------------------------------------
extern "C" void kernel_launch(void* const* d_in, const int* in_sizes, int n_in,
                              void* d_out, int out_size, void* d_ws, size_t ws_size,
                              hipStream_t stream) {
  (void)in_sizes; (void)n_in; (void)out_size; (void)ws_size;
  const float* x      = (const float*)d_in[0];  // f32 (4,4096,1024)
  const float* w_attn = (const float*)d_in[1];  // f32 (3072,1024)
  const float* w_proj = (const float*)d_in[2];  // f32 (1024,1024)
  float* out = (float*)d_out;                   // f32 (4,4096,1024)

  // ws: qkv 96 MiB | yb 32 MiB.  wab overlaps yb (dead before attn writes yb);
  // wpb overlaps qkv (written after attn reads qkv).
  // d_out scratch: xb (bf16 x, 32 MiB) + rope table (16 KiB at +32 MiB);
  // both dead before gemm2 overwrites all of out.
  short* qkv = (short*)d_ws;
  short* yb  = qkv + (size_t)16384 * 3072;
  short* wab = yb;
  short* wpb = qkv;
  short* xb  = (short*)d_out;
  float* tab = (float*)((char*)d_out + (size_t)32 * 1024 * 1024);

  cvt_bf16<<<dim3(2048), 256, 0, stream>>>(x,      xb,  (long)16384 * 1024 / 8);
  cvt_bf16<<<dim3(1024), 256, 0, stream>>>(w_attn, wab, (long)3072 * 1024 / 8);
  rope_table<<<dim3(8), 256, 0, stream>>>(tab);
  // qkv = x @ w_attn^T   (16384x3072x1024): grid 768 blocks
  gemm256<false><<<dim3(768), 512, 0, stream>>>(xb, wab, qkv, 16384, 3072, 1024);
  // chunked MFMA attention -> y (bf16): 16 heads x 4 q-stripes
  attn_stripe<<<dim3(64, 64, 4), 64, 0, stream>>>(qkv, yb, tab);
  cvt_bf16<<<dim3(512), 256, 0, stream>>>(w_proj, wpb, (long)1024 * 1024 / 8);
  // out = y @ w_proj^T   (16384x1024x1024): grid 256 blocks, f32 out
  gemm256<true><<<dim3(256), 512, 0, stream>>>(yb, wpb, out, 16384, 1024, 1024);
}